// Round 3
// baseline (378.725 us; speedup 1.0000x reference)
//
#include <hip/hip_runtime.h>
#include <stdint.h>

typedef unsigned short u16;
typedef __attribute__((ext_vector_type(4))) unsigned short u16x4;
typedef __attribute__((ext_vector_type(4))) float f32x4;
typedef __attribute__((ext_vector_type(8))) __bf16 bf16x8;

#define M_DIM 16384
#define N_DIM 2048
#define K_DIM 2048
#define NELEM (M_DIM * K_DIM)      // 33554432
#define NGROUPS (NELEM / 4)        // 8388608
#define WELEM (N_DIM * K_DIM)      // 4194304
#define PRUNE_BLOCKS 2048
#define PRUNE_ITERS (NGROUPS / (PRUNE_BLOCKS * 256))   // 16, exact

__device__ __forceinline__ u16 f2bf(float f) {
    union { float f; uint32_t u; } c; c.f = f;
    uint32_t r = c.u + 0x7FFFu + ((c.u >> 16) & 1u);   // round-to-nearest-even
    return (u16)(r >> 16);
}

// -------------------------------------------------------------------------
// Kernel 1: 2:4 prune + bf16 convert; per-block float4 partials. (unchanged)
// -------------------------------------------------------------------------
__global__ __launch_bounds__(256) void prune_kernel(const float* __restrict__ x,
                                                    u16* __restrict__ xsp,
                                                    float4* __restrict__ partials) {
    float sx = 0.f, sxx = 0.f, sp = 0.f, spp = 0.f;
    int g = blockIdx.x * 256 + threadIdx.x;
    const int stride = PRUNE_BLOCKS * 256;
#pragma unroll 4
    for (int it = 0; it < PRUNE_ITERS; ++it, g += stride) {
        float4 v = ((const float4*)x)[g];
        float a0 = v.x, a1 = v.y, a2 = v.z, a3 = v.w;
        float b0 = fabsf(a0), b1 = fabsf(a1), b2 = fabsf(a2), b3 = fabsf(a3);
        int r0 = (b1 > b0) + (b2 > b0) + (b3 > b0);
        int r1 = (b0 >= b1) + (b2 > b1) + (b3 > b1);
        int r2 = (b0 >= b2) + (b1 >= b2) + (b3 > b2);
        int r3 = (b0 >= b3) + (b1 >= b3) + (b2 >= b3);
        float k0 = (r0 < 2) ? a0 : 0.f;
        float k1 = (r1 < 2) ? a1 : 0.f;
        float k2 = (r2 < 2) ? a2 : 0.f;
        float k3 = (r3 < 2) ? a3 : 0.f;
        sx  += a0 + a1 + a2 + a3;
        sxx += a0*a0 + a1*a1 + a2*a2 + a3*a3;
        sp  += k0 + k1 + k2 + k3;
        spp += k0*k0 + k1*k1 + k2*k2 + k3*k3;
        u16x4 o;
        o.x = f2bf(k0); o.y = f2bf(k1); o.z = f2bf(k2); o.w = f2bf(k3);
        ((u16x4*)xsp)[g] = o;
    }
    for (int off = 32; off > 0; off >>= 1) {
        sx  += __shfl_down(sx,  off, 64);
        sxx += __shfl_down(sxx, off, 64);
        sp  += __shfl_down(sp,  off, 64);
        spp += __shfl_down(spp, off, 64);
    }
    __shared__ float red[4][4];
    int wid = threadIdx.x >> 6, lane = threadIdx.x & 63;
    if (lane == 0) { red[wid][0] = sx; red[wid][1] = sxx; red[wid][2] = sp; red[wid][3] = spp; }
    __syncthreads();
    if (threadIdx.x == 0) {
        float4 t;
        t.x = red[0][0] + red[1][0] + red[2][0] + red[3][0];
        t.y = red[0][1] + red[1][1] + red[2][1] + red[3][1];
        t.z = red[0][2] + red[1][2] + red[2][2] + red[3][2];
        t.w = red[0][3] + red[1][3] + red[2][3] + red[3][3];
        partials[blockIdx.x] = t;
    }
}

// -------------------------------------------------------------------------
// Kernel 1b: reduce partials -> v (unchanged)
// -------------------------------------------------------------------------
__global__ __launch_bounds__(256) void finalize_kernel(const float4* __restrict__ partials,
                                                       float* __restrict__ vout) {
    float sx = 0.f, sxx = 0.f, sp = 0.f, spp = 0.f;
#pragma unroll
    for (int i = 0; i < PRUNE_BLOCKS / 256; ++i) {
        float4 t = partials[i * 256 + threadIdx.x];
        sx += t.x; sxx += t.y; sp += t.z; spp += t.w;
    }
    for (int off = 32; off > 0; off >>= 1) {
        sx  += __shfl_down(sx,  off, 64);
        sxx += __shfl_down(sxx, off, 64);
        sp  += __shfl_down(sp,  off, 64);
        spp += __shfl_down(spp, off, 64);
    }
    __shared__ float red[4][4];
    int wid = threadIdx.x >> 6, lane = threadIdx.x & 63;
    if (lane == 0) { red[wid][0] = sx; red[wid][1] = sxx; red[wid][2] = sp; red[wid][3] = spp; }
    __syncthreads();
    if (threadIdx.x == 0) {
        float tsx  = red[0][0] + red[1][0] + red[2][0] + red[3][0];
        float tsxx = red[0][1] + red[1][1] + red[2][1] + red[3][1];
        float tsp  = red[0][2] + red[1][2] + red[2][2] + red[3][2];
        float tspp = red[0][3] + red[1][3] + red[2][3] + red[3][3];
        const float n = (float)NELEM;
        float varx = (tsxx - tsx * tsx / n) / (n - 1.f);
        float varp = (tspp - tsp * tsp / n) / (n - 1.f);
        varp = fmaxf(varp, 1e-9f);
        vout[0] = sqrtf(varx / varp);
    }
}

// -------------------------------------------------------------------------
// Kernel 2: weight fp32 -> bf16 (unchanged)
// -------------------------------------------------------------------------
__global__ __launch_bounds__(256) void wconv_kernel(const float* __restrict__ w,
                                                    u16* __restrict__ wb) {
    int i = blockIdx.x * 256 + threadIdx.x;
    float4 v = ((const float4*)w)[i];
    u16x4 o;
    o.x = f2bf(v.x); o.y = f2bf(v.y); o.z = f2bf(v.z); o.w = f2bf(v.w);
    ((u16x4*)wb)[i] = o;
}

// -------------------------------------------------------------------------
// Kernel 3: 256x256-tile, BK=64, 8-wave, 4-phase/K-tile bf16 MFMA GEMM.
// Prefetch distance = 2 K-tiles. During tile t we re-fill buf[t&1] (the
// buffer being read) for tile t+2, staging each region right after its
// last ds_read retires:
//   ph3(t): stage Bh0(t+2)                    (B region free after ph2(t))
//   ph4(t): stage Bh1(t+2)+Ah0(t+2)+Ah1(t+2)  (A region free after ph3(t))
// vmcnt(8) at end of ph4(t) keeps THIS tile's 8 loads in flight and
// enforces tile t-1's stagings (= tile t+1's data): every load gets
// 4-6 phases (~600-900 cyc) of latency cover.
// T2 swizzle both-sides (pre-swizzled global source + swizzled ds_read),
// T5 setprio around MFMA clusters, XCD-bijective block swizzle.
// -------------------------------------------------------------------------
#define GLD16(g, l) \
    __builtin_amdgcn_global_load_lds((__attribute__((address_space(1))) void*)(g), \
                                     (__attribute__((address_space(3))) void*)(l), 16, 0, 0)

#define STG(gb, ldsA, bufq, hf, kt) do { \
    const u16* _g = (gb) + (size_t)(hf) * (128 * K_DIM) + (size_t)(kt) * 64; \
    u16* _l = &(ldsA)[bufq][(hf) * 128][0] + ldst; \
    GLD16(_g, _l); \
    GLD16(_g + 64 * K_DIM, _l + 64 * 64); \
} while (0)

#define MM(va, vb, c) (c) = __builtin_amdgcn_mfma_f32_16x16x32_bf16((va), (vb), (c), 0, 0, 0)

__global__ __launch_bounds__(512, 2) void gemm_kernel(const u16* __restrict__ A,
                                                      const u16* __restrict__ B,
                                                      const float* __restrict__ vscale,
                                                      float* __restrict__ out) {
    __shared__ __align__(16) u16 As[2][256][64];   // 64 KiB
    __shared__ __align__(16) u16 Bs[2][256][64];   // 64 KiB

    const int tid  = threadIdx.x;
    const int lane = tid & 63;
    const int l15  = lane & 15;
    const int quad = lane >> 4;
    const int wid  = tid >> 6;
    const int wm   = wid >> 2;           // 0..1  (M waves)
    const int wn   = (wid & 3) * 64;     // 0,64,128,192 (N waves)

    // XCD swizzle: 512 blocks = 64 m-tiles x 8 n-tiles; 512%8==0 -> bijective
    const int b    = blockIdx.x;
    const int xcd  = b & 7;
    const int s    = b >> 3;             // 0..63
    const int m0   = (xcd * 8 + (s >> 3)) * 256;
    const int n0   = (s & 7) * 256;

    // staging geometry: row=tid>>3 (+64 for 2nd load), slot=tid&7 (16B units)
    const int r0   = tid >> 3;           // 0..63
    const int slot = tid & 7;
    const int srcs = slot ^ (r0 & 7);    // pre-swizzled global column slot
    const int ldst = tid * 8;            // LDS element offset (linear dest)
    const u16* Ab = A + (size_t)(m0 + r0) * K_DIM + srcs * 8;
    const u16* Bb = B + (size_t)(n0 + r0) * K_DIM + srcs * 8;

    // fragment-read addressing (swizzled)
    const int rsw  = (l15 & 7) << 4;          // byte XOR within 128B row
    const int xk0  = (quad * 16) ^ rsw;       // kk=0 chunk
    const int xk1  = (64 + quad * 16) ^ rsw;  // kk=1 chunk
    const int aRow = (wm * 128 + l15) * 128;  // byte offset of frag row
    const int bRow = (wn + l15) * 128;

    const float v = vscale[0];

    f32x4 acc[8][4] = {};
    bf16x8 aF[4][2], bF[2][2], bG[2][2];

    // prologue: stage tile0 AND tile1 fully (16 loads); enforce tile0 (8 left)
    STG(Ab, As, 0, 0, 0);
    STG(Ab, As, 0, 1, 0);
    STG(Bb, Bs, 0, 0, 0);
    STG(Bb, Bs, 0, 1, 0);
    STG(Ab, As, 1, 0, 1);
    STG(Ab, As, 1, 1, 1);
    STG(Bb, Bs, 1, 0, 1);
    STG(Bb, Bs, 1, 1, 1);
    asm volatile("s_waitcnt vmcnt(8)" ::: "memory");
    __builtin_amdgcn_sched_barrier(0);
    __builtin_amdgcn_s_barrier();

    const int NKT = K_DIM / 64;   // 32
    for (int t = 0; t < NKT; ++t) {
        const int pb  = (t & 1) * 32768;
        const char* pA = (const char*)As + pb + aRow;
        const char* pB = (const char*)Bs + pb + bRow;
        const int cb  = t & 1;            // buffer being read == staged for t+2

        // ---- phase 1: acc[0..3][0..1]  (reads aF qa=0, bF qb=0) ----
#pragma unroll
        for (int i = 0; i < 4; ++i) {
            aF[i][0] = *(const bf16x8*)(pA + i * 2048 + xk0);
            aF[i][1] = *(const bf16x8*)(pA + i * 2048 + xk1);
        }
#pragma unroll
        for (int j = 0; j < 2; ++j) {
            bF[j][0] = *(const bf16x8*)(pB + j * 2048 + xk0);
            bF[j][1] = *(const bf16x8*)(pB + j * 2048 + xk1);
        }
        __builtin_amdgcn_s_barrier();
        asm volatile("s_waitcnt lgkmcnt(0)" ::: "memory");
        __builtin_amdgcn_sched_barrier(0);
        __builtin_amdgcn_s_setprio(1);
#pragma unroll
        for (int i = 0; i < 4; ++i)
#pragma unroll
            for (int j = 0; j < 2; ++j) {
                MM(aF[i][0], bF[j][0], acc[i][j]);
                MM(aF[i][1], bF[j][1], acc[i][j]);
            }
        __builtin_amdgcn_s_setprio(0);
        __builtin_amdgcn_s_barrier();

        // ---- phase 2: acc[0..3][2..3]  (reads bG qb=1; reuses aF) ----
#pragma unroll
        for (int j = 0; j < 2; ++j) {
            bG[j][0] = *(const bf16x8*)(pB + 4096 + j * 2048 + xk0);
            bG[j][1] = *(const bf16x8*)(pB + 4096 + j * 2048 + xk1);
        }
        __builtin_amdgcn_s_barrier();
        asm volatile("s_waitcnt lgkmcnt(0)" ::: "memory");
        __builtin_amdgcn_sched_barrier(0);
        __builtin_amdgcn_s_setprio(1);
#pragma unroll
        for (int i = 0; i < 4; ++i)
#pragma unroll
            for (int j = 0; j < 2; ++j) {
                MM(aF[i][0], bG[j][0], acc[i][2 + j]);
                MM(aF[i][1], bG[j][1], acc[i][2 + j]);
            }
        __builtin_amdgcn_s_setprio(0);
        __builtin_amdgcn_s_barrier();

        // ---- phase 3: acc[4..7][0..1]  (reads aF qa=1; stage Bh0(t+2)) ----
#pragma unroll
        for (int i = 0; i < 4; ++i) {
            aF[i][0] = *(const bf16x8*)(pA + 8192 + i * 2048 + xk0);
            aF[i][1] = *(const bf16x8*)(pA + 8192 + i * 2048 + xk1);
        }
        if (t + 2 < NKT) STG(Bb, Bs, cb, 0, t + 2);
        __builtin_amdgcn_s_barrier();
        asm volatile("s_waitcnt lgkmcnt(0)" ::: "memory");
        __builtin_amdgcn_sched_barrier(0);
        __builtin_amdgcn_s_setprio(1);
#pragma unroll
        for (int i = 0; i < 4; ++i)
#pragma unroll
            for (int j = 0; j < 2; ++j) {
                MM(aF[i][0], bF[j][0], acc[4 + i][j]);
                MM(aF[i][1], bF[j][1], acc[4 + i][j]);
            }
        __builtin_amdgcn_s_setprio(0);
        __builtin_amdgcn_s_barrier();

        // ---- phase 4: acc[4..7][2..3]  (stage Bh1+Ah0+Ah1(t+2)) ----
        if (t + 2 < NKT) {
            STG(Bb, Bs, cb, 1, t + 2);
            STG(Ab, As, cb, 0, t + 2);
            STG(Ab, As, cb, 1, t + 2);
        }
        __builtin_amdgcn_s_barrier();
        __builtin_amdgcn_s_setprio(1);
#pragma unroll
        for (int i = 0; i < 4; ++i)
#pragma unroll
            for (int j = 0; j < 2; ++j) {
                MM(aF[i][0], bG[j][0], acc[4 + i][2 + j]);
                MM(aF[i][1], bG[j][1], acc[4 + i][2 + j]);
            }
        __builtin_amdgcn_s_setprio(0);
        if (t + 2 < NKT) { asm volatile("s_waitcnt vmcnt(8)" ::: "memory"); }
        else             { asm volatile("s_waitcnt vmcnt(0)" ::: "memory"); }
        __builtin_amdgcn_sched_barrier(0);
        __builtin_amdgcn_s_barrier();
    }

    // epilogue: C layout col = lane&15, row = quad*4 + r
    float* op = out + (size_t)(m0 + wm * 128) * N_DIM + n0 + wn;
#pragma unroll
    for (int i = 0; i < 8; ++i)
#pragma unroll
        for (int j = 0; j < 4; ++j)
#pragma unroll
            for (int r = 0; r < 4; ++r)
                op[(size_t)(i * 16 + quad * 4 + r) * N_DIM + j * 16 + l15] = acc[i][j][r] * v;
}

extern "C" void kernel_launch(void* const* d_in, const int* in_sizes, int n_in,
                              void* d_out, int out_size, void* d_ws, size_t ws_size,
                              hipStream_t stream) {
    const float* x = (const float*)d_in[0];
    const float* w = (const float*)d_in[1];
    float* out = (float*)d_out;

    u16* xsp      = (u16*)d_ws;                     // 64 MiB: bf16 x_sp [16384][2048]
    u16* wb       = xsp + NELEM;                    // 8 MiB:  bf16 W    [2048][2048]
    float4* parts = (float4*)(wb + WELEM);          // 32 KiB: per-block {sx,sxx,sp,spp}
    float* vbuf   = (float*)(parts + PRUNE_BLOCKS); // 4 B: v

    prune_kernel<<<PRUNE_BLOCKS, 256, 0, stream>>>(x, xsp, parts);
    finalize_kernel<<<1, 256, 0, stream>>>(parts, vbuf);
    wconv_kernel<<<WELEM / 4 / 256, 256, 0, stream>>>(w, wb);
    gemm_kernel<<<512, 512, 0, stream>>>(xsp, wb, vbuf, out);
}

// Round 4
// 378.389 us; speedup vs baseline: 1.0009x; 1.0009x over previous
//
#include <hip/hip_runtime.h>
#include <stdint.h>

typedef unsigned short u16;
typedef __attribute__((ext_vector_type(4))) unsigned short u16x4;
typedef __attribute__((ext_vector_type(4))) float f32x4;
typedef __attribute__((ext_vector_type(8))) __bf16 bf16x8;

#define M_DIM 16384
#define N_DIM 2048
#define K_DIM 2048
#define NELEM (M_DIM * K_DIM)      // 33554432
#define NGROUPS (NELEM / 4)        // 8388608
#define WELEM (N_DIM * K_DIM)      // 4194304
#define PRUNE_BLOCKS 2048
#define PRUNE_ITERS (NGROUPS / (PRUNE_BLOCKS * 256))   // 16, exact
#define WCONV_BLOCKS 256
#define WCONV_ITERS (WELEM / 4 / (WCONV_BLOCKS * 256)) // 16, exact

__device__ __forceinline__ u16 f2bf(float f) {
    union { float f; uint32_t u; } c; c.f = f;
    uint32_t r = c.u + 0x7FFFu + ((c.u >> 16) & 1u);   // round-to-nearest-even
    return (u16)(r >> 16);
}

// -------------------------------------------------------------------------
// Kernel 1 (fused): blocks 0..2047: 2:4 prune + bf16 convert + partials.
//                   blocks 2048..2303: weight fp32 -> bf16.
// Block-uniform branch; saves one launch and overlaps W traffic with x.
// -------------------------------------------------------------------------
__global__ __launch_bounds__(256) void prep_kernel(const float* __restrict__ x,
                                                   u16* __restrict__ xsp,
                                                   float4* __restrict__ partials,
                                                   const float* __restrict__ w,
                                                   u16* __restrict__ wb) {
    if (blockIdx.x >= PRUNE_BLOCKS) {
        // ---- wconv part ----
        int i = (blockIdx.x - PRUNE_BLOCKS) * 256 + threadIdx.x;
        const int wstride = WCONV_BLOCKS * 256;
#pragma unroll 4
        for (int it = 0; it < WCONV_ITERS; ++it, i += wstride) {
            float4 v = ((const float4*)w)[i];
            u16x4 o;
            o.x = f2bf(v.x); o.y = f2bf(v.y); o.z = f2bf(v.z); o.w = f2bf(v.w);
            ((u16x4*)wb)[i] = o;
        }
        return;
    }
    // ---- prune part ----
    float sx = 0.f, sxx = 0.f, sp = 0.f, spp = 0.f;
    int g = blockIdx.x * 256 + threadIdx.x;
    const int stride = PRUNE_BLOCKS * 256;
#pragma unroll 4
    for (int it = 0; it < PRUNE_ITERS; ++it, g += stride) {
        float4 v = ((const float4*)x)[g];
        float a0 = v.x, a1 = v.y, a2 = v.z, a3 = v.w;
        float b0 = fabsf(a0), b1 = fabsf(a1), b2 = fabsf(a2), b3 = fabsf(a3);
        int r0 = (b1 > b0) + (b2 > b0) + (b3 > b0);
        int r1 = (b0 >= b1) + (b2 > b1) + (b3 > b1);
        int r2 = (b0 >= b2) + (b1 >= b2) + (b3 > b2);
        int r3 = (b0 >= b3) + (b1 >= b3) + (b2 >= b3);
        float k0 = (r0 < 2) ? a0 : 0.f;
        float k1 = (r1 < 2) ? a1 : 0.f;
        float k2 = (r2 < 2) ? a2 : 0.f;
        float k3 = (r3 < 2) ? a3 : 0.f;
        sx  += a0 + a1 + a2 + a3;
        sxx += a0*a0 + a1*a1 + a2*a2 + a3*a3;
        sp  += k0 + k1 + k2 + k3;
        spp += k0*k0 + k1*k1 + k2*k2 + k3*k3;
        u16x4 o;
        o.x = f2bf(k0); o.y = f2bf(k1); o.z = f2bf(k2); o.w = f2bf(k3);
        ((u16x4*)xsp)[g] = o;
    }
    for (int off = 32; off > 0; off >>= 1) {
        sx  += __shfl_down(sx,  off, 64);
        sxx += __shfl_down(sxx, off, 64);
        sp  += __shfl_down(sp,  off, 64);
        spp += __shfl_down(spp, off, 64);
    }
    __shared__ float red[4][4];
    int wid = threadIdx.x >> 6, lane = threadIdx.x & 63;
    if (lane == 0) { red[wid][0] = sx; red[wid][1] = sxx; red[wid][2] = sp; red[wid][3] = spp; }
    __syncthreads();
    if (threadIdx.x == 0) {
        float4 t;
        t.x = red[0][0] + red[1][0] + red[2][0] + red[3][0];
        t.y = red[0][1] + red[1][1] + red[2][1] + red[3][1];
        t.z = red[0][2] + red[1][2] + red[2][2] + red[3][2];
        t.w = red[0][3] + red[1][3] + red[2][3] + red[3][3];
        partials[blockIdx.x] = t;
    }
}

// -------------------------------------------------------------------------
// Kernel 1b: reduce partials -> v (unchanged)
// -------------------------------------------------------------------------
__global__ __launch_bounds__(256) void finalize_kernel(const float4* __restrict__ partials,
                                                       float* __restrict__ vout) {
    float sx = 0.f, sxx = 0.f, sp = 0.f, spp = 0.f;
#pragma unroll
    for (int i = 0; i < PRUNE_BLOCKS / 256; ++i) {
        float4 t = partials[i * 256 + threadIdx.x];
        sx += t.x; sxx += t.y; sp += t.z; spp += t.w;
    }
    for (int off = 32; off > 0; off >>= 1) {
        sx  += __shfl_down(sx,  off, 64);
        sxx += __shfl_down(sxx, off, 64);
        sp  += __shfl_down(sp,  off, 64);
        spp += __shfl_down(spp, off, 64);
    }
    __shared__ float red[4][4];
    int wid = threadIdx.x >> 6, lane = threadIdx.x & 63;
    if (lane == 0) { red[wid][0] = sx; red[wid][1] = sxx; red[wid][2] = sp; red[wid][3] = spp; }
    __syncthreads();
    if (threadIdx.x == 0) {
        float tsx  = red[0][0] + red[1][0] + red[2][0] + red[3][0];
        float tsxx = red[0][1] + red[1][1] + red[2][1] + red[3][1];
        float tsp  = red[0][2] + red[1][2] + red[2][2] + red[3][2];
        float tspp = red[0][3] + red[1][3] + red[2][3] + red[3][3];
        const float n = (float)NELEM;
        float varx = (tsxx - tsx * tsx / n) / (n - 1.f);
        float varp = (tspp - tsp * tsp / n) / (n - 1.f);
        varp = fmaxf(varp, 1e-9f);
        vout[0] = sqrtf(varx / varp);
    }
}

// -------------------------------------------------------------------------
// Kernel 3: 256x256-tile, BK=64, 8-wave, 4-phase/K-tile bf16 MFMA GEMM.
// BYTE-IDENTICAL to round 3 (145.5 µs, 946 TF, MfmaUtil 39.7, conflicts 0).
// Prefetch distance = 2 K-tiles; vmcnt(8) counted wait; T2 both-sides
// swizzle; T5 setprio; XCD-bijective block swizzle.
// -------------------------------------------------------------------------
#define GLD16(g, l) \
    __builtin_amdgcn_global_load_lds((__attribute__((address_space(1))) void*)(g), \
                                     (__attribute__((address_space(3))) void*)(l), 16, 0, 0)

#define STG(gb, ldsA, bufq, hf, kt) do { \
    const u16* _g = (gb) + (size_t)(hf) * (128 * K_DIM) + (size_t)(kt) * 64; \
    u16* _l = &(ldsA)[bufq][(hf) * 128][0] + ldst; \
    GLD16(_g, _l); \
    GLD16(_g + 64 * K_DIM, _l + 64 * 64); \
} while (0)

#define MM(va, vb, c) (c) = __builtin_amdgcn_mfma_f32_16x16x32_bf16((va), (vb), (c), 0, 0, 0)

__global__ __launch_bounds__(512, 2) void gemm_kernel(const u16* __restrict__ A,
                                                      const u16* __restrict__ B,
                                                      const float* __restrict__ vscale,
                                                      float* __restrict__ out) {
    __shared__ __align__(16) u16 As[2][256][64];   // 64 KiB
    __shared__ __align__(16) u16 Bs[2][256][64];   // 64 KiB

    const int tid  = threadIdx.x;
    const int lane = tid & 63;
    const int l15  = lane & 15;
    const int quad = lane >> 4;
    const int wid  = tid >> 6;
    const int wm   = wid >> 2;           // 0..1  (M waves)
    const int wn   = (wid & 3) * 64;     // 0,64,128,192 (N waves)

    // XCD swizzle: 512 blocks = 64 m-tiles x 8 n-tiles; 512%8==0 -> bijective
    const int b    = blockIdx.x;
    const int xcd  = b & 7;
    const int s    = b >> 3;             // 0..63
    const int m0   = (xcd * 8 + (s >> 3)) * 256;
    const int n0   = (s & 7) * 256;

    // staging geometry: row=tid>>3 (+64 for 2nd load), slot=tid&7 (16B units)
    const int r0   = tid >> 3;           // 0..63
    const int slot = tid & 7;
    const int srcs = slot ^ (r0 & 7);    // pre-swizzled global column slot
    const int ldst = tid * 8;            // LDS element offset (linear dest)
    const u16* Ab = A + (size_t)(m0 + r0) * K_DIM + srcs * 8;
    const u16* Bb = B + (size_t)(n0 + r0) * K_DIM + srcs * 8;

    // fragment-read addressing (swizzled)
    const int rsw  = (l15 & 7) << 4;          // byte XOR within 128B row
    const int xk0  = (quad * 16) ^ rsw;       // kk=0 chunk
    const int xk1  = (64 + quad * 16) ^ rsw;  // kk=1 chunk
    const int aRow = (wm * 128 + l15) * 128;  // byte offset of frag row
    const int bRow = (wn + l15) * 128;

    const float v = vscale[0];

    f32x4 acc[8][4] = {};
    bf16x8 aF[4][2], bF[2][2], bG[2][2];

    // prologue: stage tile0 AND tile1 fully (16 loads); enforce tile0 (8 left)
    STG(Ab, As, 0, 0, 0);
    STG(Ab, As, 0, 1, 0);
    STG(Bb, Bs, 0, 0, 0);
    STG(Bb, Bs, 0, 1, 0);
    STG(Ab, As, 1, 0, 1);
    STG(Ab, As, 1, 1, 1);
    STG(Bb, Bs, 1, 0, 1);
    STG(Bb, Bs, 1, 1, 1);
    asm volatile("s_waitcnt vmcnt(8)" ::: "memory");
    __builtin_amdgcn_sched_barrier(0);
    __builtin_amdgcn_s_barrier();

    const int NKT = K_DIM / 64;   // 32
    for (int t = 0; t < NKT; ++t) {
        const int pb  = (t & 1) * 32768;
        const char* pA = (const char*)As + pb + aRow;
        const char* pB = (const char*)Bs + pb + bRow;
        const int cb  = t & 1;            // buffer being read == staged for t+2

        // ---- phase 1: acc[0..3][0..1]  (reads aF qa=0, bF qb=0) ----
#pragma unroll
        for (int i = 0; i < 4; ++i) {
            aF[i][0] = *(const bf16x8*)(pA + i * 2048 + xk0);
            aF[i][1] = *(const bf16x8*)(pA + i * 2048 + xk1);
        }
#pragma unroll
        for (int j = 0; j < 2; ++j) {
            bF[j][0] = *(const bf16x8*)(pB + j * 2048 + xk0);
            bF[j][1] = *(const bf16x8*)(pB + j * 2048 + xk1);
        }
        __builtin_amdgcn_s_barrier();
        asm volatile("s_waitcnt lgkmcnt(0)" ::: "memory");
        __builtin_amdgcn_sched_barrier(0);
        __builtin_amdgcn_s_setprio(1);
#pragma unroll
        for (int i = 0; i < 4; ++i)
#pragma unroll
            for (int j = 0; j < 2; ++j) {
                MM(aF[i][0], bF[j][0], acc[i][j]);
                MM(aF[i][1], bF[j][1], acc[i][j]);
            }
        __builtin_amdgcn_s_setprio(0);
        __builtin_amdgcn_s_barrier();

        // ---- phase 2: acc[0..3][2..3]  (reads bG qb=1; reuses aF) ----
#pragma unroll
        for (int j = 0; j < 2; ++j) {
            bG[j][0] = *(const bf16x8*)(pB + 4096 + j * 2048 + xk0);
            bG[j][1] = *(const bf16x8*)(pB + 4096 + j * 2048 + xk1);
        }
        __builtin_amdgcn_s_barrier();
        asm volatile("s_waitcnt lgkmcnt(0)" ::: "memory");
        __builtin_amdgcn_sched_barrier(0);
        __builtin_amdgcn_s_setprio(1);
#pragma unroll
        for (int i = 0; i < 4; ++i)
#pragma unroll
            for (int j = 0; j < 2; ++j) {
                MM(aF[i][0], bG[j][0], acc[i][2 + j]);
                MM(aF[i][1], bG[j][1], acc[i][2 + j]);
            }
        __builtin_amdgcn_s_setprio(0);
        __builtin_amdgcn_s_barrier();

        // ---- phase 3: acc[4..7][0..1]  (reads aF qa=1; stage Bh0(t+2)) ----
#pragma unroll
        for (int i = 0; i < 4; ++i) {
            aF[i][0] = *(const bf16x8*)(pA + 8192 + i * 2048 + xk0);
            aF[i][1] = *(const bf16x8*)(pA + 8192 + i * 2048 + xk1);
        }
        if (t + 2 < NKT) STG(Bb, Bs, cb, 0, t + 2);
        __builtin_amdgcn_s_barrier();
        asm volatile("s_waitcnt lgkmcnt(0)" ::: "memory");
        __builtin_amdgcn_sched_barrier(0);
        __builtin_amdgcn_s_setprio(1);
#pragma unroll
        for (int i = 0; i < 4; ++i)
#pragma unroll
            for (int j = 0; j < 2; ++j) {
                MM(aF[i][0], bF[j][0], acc[4 + i][j]);
                MM(aF[i][1], bF[j][1], acc[4 + i][j]);
            }
        __builtin_amdgcn_s_setprio(0);
        __builtin_amdgcn_s_barrier();

        // ---- phase 4: acc[4..7][2..3]  (stage Bh1+Ah0+Ah1(t+2)) ----
        if (t + 2 < NKT) {
            STG(Bb, Bs, cb, 1, t + 2);
            STG(Ab, As, cb, 0, t + 2);
            STG(Ab, As, cb, 1, t + 2);
        }
        __builtin_amdgcn_s_barrier();
        __builtin_amdgcn_s_setprio(1);
#pragma unroll
        for (int i = 0; i < 4; ++i)
#pragma unroll
            for (int j = 0; j < 2; ++j) {
                MM(aF[i][0], bG[j][0], acc[4 + i][2 + j]);
                MM(aF[i][1], bG[j][1], acc[4 + i][2 + j]);
            }
        __builtin_amdgcn_s_setprio(0);
        if (t + 2 < NKT) { asm volatile("s_waitcnt vmcnt(8)" ::: "memory"); }
        else             { asm volatile("s_waitcnt vmcnt(0)" ::: "memory"); }
        __builtin_amdgcn_sched_barrier(0);
        __builtin_amdgcn_s_barrier();
    }

    // epilogue: C layout col = lane&15, row = quad*4 + r
    float* op = out + (size_t)(m0 + wm * 128) * N_DIM + n0 + wn;
#pragma unroll
    for (int i = 0; i < 8; ++i)
#pragma unroll
        for (int j = 0; j < 4; ++j)
#pragma unroll
            for (int r = 0; r < 4; ++r)
                op[(size_t)(i * 16 + quad * 4 + r) * N_DIM + j * 16 + l15] = acc[i][j][r] * v;
}

extern "C" void kernel_launch(void* const* d_in, const int* in_sizes, int n_in,
                              void* d_out, int out_size, void* d_ws, size_t ws_size,
                              hipStream_t stream) {
    const float* x = (const float*)d_in[0];
    const float* w = (const float*)d_in[1];
    float* out = (float*)d_out;

    u16* xsp      = (u16*)d_ws;                     // 64 MiB: bf16 x_sp [16384][2048]
    u16* wb       = xsp + NELEM;                    // 8 MiB:  bf16 W    [2048][2048]
    float4* parts = (float4*)(wb + WELEM);          // 32 KiB: per-block {sx,sxx,sp,spp}
    float* vbuf   = (float*)(parts + PRUNE_BLOCKS); // 4 B: v

    prep_kernel<<<PRUNE_BLOCKS + WCONV_BLOCKS, 256, 0, stream>>>(x, xsp, parts, w, wb);
    finalize_kernel<<<1, 256, 0, stream>>>(parts, vbuf);
    gemm_kernel<<<512, 512, 0, stream>>>(xsp, wb, vbuf, out);
}